// Round 1
// baseline (368.592 us; speedup 1.0000x reference)
//
#include <hip/hip_runtime.h>
#include <stdint.h>

// ---------------------------------------------------------------------------
// CAWN fused forward, round 5: attn occupancy fix.
//   prep    : wkfrag (B-operand frags of wk_eff, bf16) + Gt bf16 [512][2048]
//   attn4   : 512-thread blocks (was 256) -> 16 waves/CU at the same 76 KB
//             LDS (2 blocks/CU). Staging 8 steps, scores on waves 0..3,
//             ctx N-tiles split across 8 waves. Same math order as attn3.
//   gemm3   : out_pre = ctx @ G, 32x64 tiles, 512 blocks (2/CU)
//   epilogue4: 4 batches/block, 512 blocks
// ---------------------------------------------------------------------------

#define DEV static __device__ __forceinline__

typedef __attribute__((ext_vector_type(8))) short short8;
typedef __attribute__((ext_vector_type(4))) float floatx4;

DEV unsigned short f2bf(float f) {
    unsigned int x; __builtin_memcpy(&x, &f, 4);
    return (unsigned short)((x + 0x7fffu + ((x >> 16) & 1u)) >> 16);   // RNE
}
// pack two fp32 -> bf16 pair (truncation) in ONE v_perm_b32
DEV unsigned int pk2(float hi, float lo) {
    unsigned int a, b;
    __builtin_memcpy(&a, &hi, 4); __builtin_memcpy(&b, &lo, 4);
    return __builtin_amdgcn_perm(a, b, 0x07060302u);
}

// ---------------------------------------------------------------------------
// prep: blocks 0..255 -> Gt ; blocks 256..263 -> wkfrag
// wkfrag layout: [kk 0..15][quad 0..3][l16 0..15][j 0..7] bf16 (16 KB),
//   element = sum_d Wk[c,h*128+d]*w_map[128+d] at c=kk*32+quad*8+j, head=l16
//   (l16>=4 zero-filled).
// Gt[j][r] = sum_d Wv[c][h*128+d]*fc_w[h*128+d][j],  r = h*512+c.
// ---------------------------------------------------------------------------
__global__ __launch_bounds__(256) void prep(const float* __restrict__ Wk,
                                            const float* __restrict__ w_map,
                                            const float* __restrict__ Wv,
                                            const float* __restrict__ fc_w,
                                            unsigned short* __restrict__ wkfrag,
                                            unsigned short* __restrict__ Gt) {
    const int t = threadIdx.x;
    if (blockIdx.x >= 256) {          // ---- wkfrag path (8 blocks) ----
        int n = (blockIdx.x - 256) * 256 + t;   // 0..2047
        int h = n >> 9, c = n & 511;
        const float* wrow = Wk + (size_t)c * 512 + h * 128;
        const float* wm = w_map + 128;
        float acc = 0.f;
        #pragma unroll 8
        for (int d = 0; d < 128; d += 4) {
            float4 a = *(const float4*)(wrow + d);
            float4 b = *(const float4*)(wm + d);
            acc += a.x * b.x + a.y * b.y + a.z * b.z + a.w * b.w;
        }
        int kk = c >> 5, quad = (c >> 3) & 3, j = c & 7;
        unsigned short* p = wkfrag + (((kk * 4 + quad) * 16) + h) * 8 + j;
        p[0] = f2bf(acc);
        p[32] = 0; p[64] = 0; p[96] = 0;      // l16 = h+4, h+8, h+12
        return;
    }
    // ---- Gt path ----
    __shared__ float wv[8 * 128];
    int r0 = blockIdx.x * 8;
    int h = r0 >> 9, c0 = r0 & 511;
    {
        int idx = t * 4;
        int i = idx >> 7, d = idx & 127;
        *(float4*)&wv[idx] = *(const float4*)(Wv + (size_t)(c0 + i) * 512 + h * 128 + d);
    }
    __syncthreads();
    float acc[8][2];
    #pragma unroll
    for (int i = 0; i < 8; i++) { acc[i][0] = 0.f; acc[i][1] = 0.f; }
    const float* fw = fc_w + (size_t)(h * 128) * 512 + t;
    for (int d = 0; d < 128; d++) {
        float w0 = fw[(size_t)d * 512];
        float w1 = fw[(size_t)d * 512 + 256];
        #pragma unroll
        for (int i = 0; i < 8; i++) {
            float a = wv[i * 128 + d];
            acc[i][0] += a * w0;
            acc[i][1] += a * w1;
        }
    }
    uint4 o0, o1;
    o0.x = ((unsigned int)f2bf(acc[1][0]) << 16) | f2bf(acc[0][0]);
    o0.y = ((unsigned int)f2bf(acc[3][0]) << 16) | f2bf(acc[2][0]);
    o0.z = ((unsigned int)f2bf(acc[5][0]) << 16) | f2bf(acc[4][0]);
    o0.w = ((unsigned int)f2bf(acc[7][0]) << 16) | f2bf(acc[6][0]);
    o1.x = ((unsigned int)f2bf(acc[1][1]) << 16) | f2bf(acc[0][1]);
    o1.y = ((unsigned int)f2bf(acc[3][1]) << 16) | f2bf(acc[2][1]);
    o1.z = ((unsigned int)f2bf(acc[5][1]) << 16) | f2bf(acc[4][1]);
    o1.w = ((unsigned int)f2bf(acc[7][1]) << 16) | f2bf(acc[6][1]);
    *(uint4*)(Gt + (size_t)t * 2048 + r0)         = o0;
    *(uint4*)(Gt + (size_t)(t + 256) * 2048 + r0) = o1;
}

// ---------------------------------------------------------------------------
// attn4: 1 batch per 512-thread block (8 waves), 2 blocks/CU (LDS 76 KB).
// LDS kinb[64][512] bf16, 16B group g of row r stored at g ^ (r&7) ^ ((r>>3)&7).
// Stage: 8 steps, wave w handles row step*8+w (full 512 cols per wave).
// Scores: waves 0..3 (wave w -> M-rows w*16..+15, 16 MFMAs) as in attn3.
// Ctx: wave w -> N-cols w*64..+63 (4 MFMA N-tiles per wave).
// ---------------------------------------------------------------------------
__global__ __launch_bounds__(512, 4) void attn4(const float* __restrict__ seq,
                                                const float* __restrict__ seq_t,
                                                const float* __restrict__ seq_e,
                                                const float* __restrict__ seq_p,
                                                const int* __restrict__ mask,
                                                const unsigned short* __restrict__ wkfrag,
                                                float* __restrict__ attn_out,
                                                unsigned short* __restrict__ ctxb) {
    __shared__ __align__(16) unsigned short kinb[64 * 512];   // 64 KB
    __shared__ float sd[64 * 5];      // scores [row][head], pad-5
    __shared__ __align__(16) float pb[256];        // probs [head][row]
    __shared__ __align__(16) float cb[4 * 512];    // ctx fp32 [head][col]
    const int b = blockIdx.x, t = threadIdx.x;
    const int w = t >> 6, l16 = t & 15, quad = (t >> 4) & 3;

    // ---- stage k_in as bf16 into swizzled LDS (8 steps, 512 threads) ----
    #pragma unroll
    for (int step = 0; step < 8; step++) {
        int g = step * 512 + t;           // 16B-group id, 0..4095
        int row = g >> 6, gcol = g & 63;
        int seg = gcol >> 4;
        const float* p = (seg == 0 ? seq : seg == 1 ? seq_e : seg == 2 ? seq_t : seq_p)
                         + (size_t)b * 8192 + row * 128 + (gcol & 15) * 8;
        float4 v0 = *(const float4*)p;
        float4 v1 = *(const float4*)(p + 4);
        uint4 pk;
        pk.x = pk2(v0.y, v0.x); pk.y = pk2(v0.w, v0.z);
        pk.z = pk2(v1.y, v1.x); pk.w = pk2(v1.w, v1.z);
        int ps = gcol ^ (row & 7) ^ ((row >> 3) & 7);
        *(uint4*)&kinb[row * 512 + ps * 8] = pk;
    }
    __syncthreads();

    // ---- scores via MFMA (waves 0..3): S[64 x 4] = kinb @ wk_eff ----
    if (w < 4) {
        short8 wkf[16];
        #pragma unroll
        for (int kk = 0; kk < 16; kk++)
            wkf[kk] = *(const short8*)(wkfrag + (((kk * 4 + quad) * 16) + l16) * 8);
        floatx4 sacc = {0.f, 0.f, 0.f, 0.f};
        const int srow = w * 16 + l16;
        const int rs = (srow & 7) ^ ((srow >> 3) & 7);
        #pragma unroll
        for (int kk = 0; kk < 16; kk++) {
            short8 af = *(const short8*)&kinb[srow * 512 + ((kk * 4 + quad) ^ rs) * 8];
            sacc = __builtin_amdgcn_mfma_f32_16x16x32_bf16(af, wkf[kk], sacc, 0, 0, 0);
        }
        if (l16 < 4) {                // C: col(l16)=head, row=quad*4+r
            #pragma unroll
            for (int r = 0; r < 4; r++) sd[(w * 16 + quad * 4 + r) * 5 + l16] = sacc[r];
        }
    }
    __syncthreads();

    // ---- masked softmax: wave h = head h, lane = row; ONE reduce ----
    if (t < 256) {
        int row = t & 63, head = t >> 6;
        float s = sd[row * 5 + head];
        float e = mask[b * 64 + row] ? 0.f : __expf(s);
        float sum = e;
        #pragma unroll
        for (int m = 32; m; m >>= 1) sum += __shfl_xor(sum, m, 64);
        float pr = e / sum;
        attn_out[b * 256 + t] = pr;   // [B][H][1][64], t = head*64+row
        pb[t] = pr;                   // pb[head*64+row]
    }
    __syncthreads();

    // ---- ctx via MFMA: ctx[4 x 512] = P[16pad x 64] @ kinb[64 x 512] ----
    // wave w owns cols w*64 .. w*64+63 (4 N-tiles)
    floatx4 cacc[4];
    #pragma unroll
    for (int nt = 0; nt < 4; nt++) cacc[nt] = (floatx4){0.f, 0.f, 0.f, 0.f};
    #pragma unroll
    for (int s = 0; s < 2; s++) {
        short8 afr = {0, 0, 0, 0, 0, 0, 0, 0};
        if (l16 < 4) {                // A-frag: P[head l16][k = s*32+quad*8+j]
            const float* pp = pb + l16 * 64 + s * 32 + quad * 8;
            float4 u0 = *(const float4*)pp;
            float4 u1 = *(const float4*)(pp + 4);
            uint4 tmp;
            tmp.x = pk2(u0.y, u0.x); tmp.y = pk2(u0.w, u0.z);
            tmp.z = pk2(u1.y, u1.x); tmp.w = pk2(u1.w, u1.z);
            __builtin_memcpy(&afr, &tmp, 16);
        }
        const int sq = s * 4 + quad;
        #pragma unroll
        for (int nt = 0; nt < 4; nt++) {
            const int c = w * 64 + nt * 16 + l16;
            const int gc = c >> 3, co = c & 7;
            short8 bfr;                // B-frag: kinb[k = s*32+quad*8+j][c]
            #pragma unroll
            for (int j = 0; j < 8; j++) {
                int r = s * 32 + quad * 8 + j;
                bfr[j] = (short)kinb[r * 512 + (gc ^ j ^ sq) * 8 + co];
            }
            cacc[nt] = __builtin_amdgcn_mfma_f32_16x16x32_bf16(afr, bfr, cacc[nt], 0, 0, 0);
        }
    }
    if (quad == 0) {                  // C rows 0..3 = heads, col = nt*16+l16
        #pragma unroll
        for (int nt = 0; nt < 4; nt++) {
            int c = w * 64 + nt * 16 + l16;
            #pragma unroll
            for (int r = 0; r < 4; r++) cb[r * 512 + c] = cacc[nt][r];
        }
    }
    __syncthreads();
    {   // pack cb -> ctxb bf16 row b (coalesced, 512 threads x 8 B)
        const float* pp = cb + t * 4;
        float4 u = *(const float4*)pp;
        uint2 pk;
        pk.x = pk2(u.y, u.x); pk.y = pk2(u.w, u.z);
        *(uint2*)(ctxb + (size_t)b * 2048 + t * 4) = pk;
    }
}

// ---------------------------------------------------------------------------
// gemm3: out_pre[2048x512] = ctx[2048x2048] @ G, B as Gt[n][k].
// 32(M) x 64(N) tile, BK=64, register prefetch.  grid (64,8) x 256 -> 2/CU.
// ---------------------------------------------------------------------------
__global__ __launch_bounds__(256) void gemm3(const unsigned short* __restrict__ A,
                                             const unsigned short* __restrict__ Bt,
                                             float* __restrict__ C) {
    __shared__ __align__(16) unsigned short As[32 * 64];
    __shared__ __align__(16) unsigned short Bs[64 * 64];
    const int t = threadIdx.x;
    const int m0 = blockIdx.x * 32, n0 = blockIdx.y * 64;
    const int w = t >> 6, lane = t & 63, quad = lane >> 4, l16 = lane & 15;
    const int wm = w >> 1, wn = w & 1;
    const int ar = t >> 3, g = t & 7;
    const int br0 = t >> 3, br1 = br0 + 32;
    const unsigned short* pa  = A  + (size_t)(m0 + ar) * 2048 + g * 8;
    const unsigned short* pb0 = Bt + (size_t)(n0 + br0) * 2048 + g * 8;
    const unsigned short* pb1 = Bt + (size_t)(n0 + br1) * 2048 + g * 8;
    const int da  = ar * 64 + (g ^ (ar & 7)) * 8;
    const int db0 = br0 * 64 + (g ^ (br0 & 7)) * 8;
    const int db1 = br1 * 64 + (g ^ (br1 & 7)) * 8;
    floatx4 acc0 = {0.f,0.f,0.f,0.f}, acc1 = {0.f,0.f,0.f,0.f};
    uint4 va = *(const uint4*)pa, vb0 = *(const uint4*)pb0, vb1 = *(const uint4*)pb1;
    const int ra = wm * 16 + l16, rb = wn * 32 + l16;
    for (int k0 = 0; k0 < 2048; k0 += 64) {
        *(uint4*)&As[da] = va; *(uint4*)&Bs[db0] = vb0; *(uint4*)&Bs[db1] = vb1;
        __syncthreads();
        if (k0 < 1984) {
            va  = *(const uint4*)(pa  + k0 + 64);
            vb0 = *(const uint4*)(pb0 + k0 + 64);
            vb1 = *(const uint4*)(pb1 + k0 + 64);
        }
        #pragma unroll
        for (int ks = 0; ks < 2; ks++) {
            int grp = ks * 4 + quad;
            short8 a  = *(const short8*)&As[ra * 64 + ((grp ^ (ra & 7)) * 8)];
            short8 b0 = *(const short8*)&Bs[rb * 64 + ((grp ^ (rb & 7)) * 8)];
            short8 b1 = *(const short8*)&Bs[(rb + 16) * 64 + ((grp ^ (rb & 7)) * 8)];
            acc0 = __builtin_amdgcn_mfma_f32_16x16x32_bf16(a, b0, acc0, 0, 0, 0);
            acc1 = __builtin_amdgcn_mfma_f32_16x16x32_bf16(a, b1, acc1, 0, 0, 0);
        }
        __syncthreads();
    }
    float* cp = C + (size_t)(m0 + wm * 16) * 512 + n0 + wn * 32;
    #pragma unroll
    for (int r = 0; r < 4; r++) {
        int rr = quad * 4 + r;
        cp[(size_t)rr * 512 + l16]      = acc0[r];
        cp[(size_t)rr * 512 + l16 + 16] = acc1[r];
    }
}

// ---------------------------------------------------------------------------
// epilogue4: 4 batches per block, 512 blocks.
// ---------------------------------------------------------------------------
__global__ __launch_bounds__(256) void epilogue4(const float* __restrict__ out_pre,
                                                 const float* __restrict__ src,
                                                 const float* __restrict__ src_t,
                                                 const float* __restrict__ src_p,
                                                 const float* __restrict__ fc_b,
                                                 const float* __restrict__ ln_g,
                                                 const float* __restrict__ ln_b,
                                                 const float* __restrict__ fc1_w,
                                                 const float* __restrict__ fc1_b,
                                                 const float* __restrict__ fc2_w,
                                                 const float* __restrict__ fc2_b,
                                                 float* __restrict__ z_out) {
    __shared__ float oln[4][512];
    __shared__ float t1p[2][4][128];
    __shared__ float t1[4][128];
    const int t = threadIdx.x;
    const int b0 = blockIdx.x * 4;
    const int w = t >> 6, lane = t & 63;

    {   // leaky_relu(out_pre + fc_b) + q_in, layernorm.  wave w -> batch b0+w
        int b = b0 + w;
        float vals[8];
        float sum = 0.f, ssq = 0.f;
        #pragma unroll
        for (int i = 0; i < 8; i++) {
            int c = lane + (i << 6);
            float v = out_pre[(size_t)b * 512 + c] + fc_b[c];
            v = (v > 0.f) ? v : 0.2f * v;
            float q;
            int seg = c >> 7;
            if (seg == 0)      q = src[b * 128 + c];
            else if (seg == 1) q = 0.f;
            else if (seg == 2) q = src_t[b * 128 + c - 256];
            else               q = src_p[b * 128 + c - 384];
            v += q;
            vals[i] = v;
            sum += v; ssq += v * v;
        }
        #pragma unroll
        for (int m = 32; m; m >>= 1) {
            sum += __shfl_xor(sum, m, 64);
            ssq += __shfl_xor(ssq, m, 64);
        }
        float mu = sum * (1.f / 512.f);
        float var = ssq * (1.f / 512.f) - mu * mu;
        float rstd = rsqrtf(var + 1e-5f);
        #pragma unroll
        for (int i = 0; i < 8; i++) {
            int c = lane + (i << 6);
            oln[w][c] = (vals[i] - mu) * rstd * ln_g[c] + ln_b[c];
        }
    }
    __syncthreads();

    {   // t1 = relu([oln, src] @ fc1_w + fc1_b), K=640 over 2 halves
        int j = t & 127, hf = t >> 7;
        float acc[4];
        #pragma unroll
        for (int bb = 0; bb < 4; bb++) acc[bb] = (hf == 0) ? fc1_b[j] : 0.f;
        int i0 = hf * 320;
        for (int ic = 0; ic < 320; ic += 4) {
            int i = i0 + ic;
            float w0 = fc1_w[(size_t)(i + 0) * 128 + j];
            float w1 = fc1_w[(size_t)(i + 1) * 128 + j];
            float w2 = fc1_w[(size_t)(i + 2) * 128 + j];
            float w3 = fc1_w[(size_t)(i + 3) * 128 + j];
            #pragma unroll
            for (int bb = 0; bb < 4; bb++) {
                float4 x;
                if (i < 512) x = *(const float4*)&oln[bb][i];
                else         x = *(const float4*)(src + (size_t)(b0 + bb) * 128 + (i - 512));
                acc[bb] += x.x * w0 + x.y * w1 + x.z * w2 + x.w * w3;
            }
        }
        #pragma unroll
        for (int bb = 0; bb < 4; bb++) t1p[hf][bb][j] = acc[bb];
    }
    __syncthreads();
    {
        int j = t & 127, g = t >> 7;
        #pragma unroll
        for (int e = 0; e < 2; e++) {
            int bb = g * 2 + e;
            t1[bb][j] = fmaxf(t1p[0][bb][j] + t1p[1][bb][j], 0.f);
        }
    }
    __syncthreads();
    {   // z = t1 @ fc2_w + fc2_b
        int j = t & 127, g = t >> 7;
        float acc[2];
        #pragma unroll
        for (int e = 0; e < 2; e++) acc[e] = fc2_b[j];
        for (int i = 0; i < 128; i++) {
            float w2 = fc2_w[(size_t)i * 128 + j];
            #pragma unroll
            for (int e = 0; e < 2; e++) acc[e] += t1[g * 2 + e][i] * w2;
        }
        #pragma unroll
        for (int e = 0; e < 2; e++)
            z_out[(size_t)(b0 + g * 2 + e) * 128 + j] = acc[e];
    }
}

// ---------------------------------------------------------------------------
extern "C" void kernel_launch(void* const* d_in, const int* in_sizes, int n_in,
                              void* d_out, int out_size, void* d_ws, size_t ws_size,
                              hipStream_t stream) {
    const float* src   = (const float*)d_in[0];
    const float* src_t = (const float*)d_in[1];
    const float* src_p = (const float*)d_in[2];
    const float* seq   = (const float*)d_in[3];
    const float* seq_t = (const float*)d_in[4];
    const float* seq_e = (const float*)d_in[5];
    const float* seq_p = (const float*)d_in[6];
    const int*   mask  = (const int*)d_in[7];
    // d_in[8] = Wq: unused (q_score constant over the softmax axis)
    const float* Wk    = (const float*)d_in[9];
    const float* Wv    = (const float*)d_in[10];
    const float* w_map = (const float*)d_in[11];
    const float* fc_w  = (const float*)d_in[12];
    const float* fc_b  = (const float*)d_in[13];
    const float* ln_g  = (const float*)d_in[14];
    const float* ln_b  = (const float*)d_in[15];
    const float* fc1_w = (const float*)d_in[16];
    const float* fc1_b = (const float*)d_in[17];
    const float* fc2_w = (const float*)d_in[18];
    const float* fc2_b = (const float*)d_in[19];

    float* z_out    = (float*)d_out;                  // [2048,1,128]
    float* attn_out = (float*)d_out + 2048 * 128;     // [2048,4,1,64]

    char* ws = (char*)d_ws;
    unsigned short* wkfrag  = (unsigned short*)ws;                           // 16 KB
    unsigned short* Gt      = (unsigned short*)(ws + 65536);                 // 2 MB
    unsigned short* ctxb    = (unsigned short*)(ws + 65536 + (2u << 20));    // 8 MB
    float*          out_pre = (float*)(ws + 65536 + (10u << 20));            // 4 MB

    hipLaunchKernelGGL(prep, dim3(264), dim3(256), 0, stream,
                       Wk, w_map, Wv, fc_w, wkfrag, Gt);
    hipLaunchKernelGGL(attn4, dim3(2048), dim3(512), 0, stream,
                       seq, seq_t, seq_e, seq_p, mask, wkfrag, attn_out, ctxb);
    hipLaunchKernelGGL(gemm3, dim3(64, 8), dim3(256), 0, stream, ctxb, Gt, out_pre);
    hipLaunchKernelGGL(epilogue4, dim3(512), dim3(256), 0, stream, out_pre,
                       src, src_t, src_p, fc_b, ln_g, ln_b,
                       fc1_w, fc1_b, fc2_w, fc2_b, z_out);
}